// Round 1
// baseline (9165.111 us; speedup 1.0000x reference)
//
#include <hip/hip_runtime.h>
#include <hip/hip_bf16.h>
#include <cstdint>
#include <cstddef>

#define N_   64
#define T_   128
#define V_   20000
#define E_   16
#define H_   256
#define G4   1024      // 4*H
#define NT   8192      // N_*T_
#define NPAD 20096     // 157*128, W2 rows padded to tile multiple

typedef __attribute__((ext_vector_type(8))) short short8;
typedef __attribute__((ext_vector_type(4))) float f32x4;

__device__ __forceinline__ float sigmoidf_(float x) {
    return 1.0f / (1.0f + __expf(-x));
}

// ---------------- prep kernels ----------------

// in [R][C] row-major -> out [C][R]
__global__ void k_transpose(const float* __restrict__ in, float* __restrict__ out,
                            int R, int C) {
    int i = blockIdx.x * blockDim.x + threadIdx.x;
    if (i < R * C) {
        int r = i / C, c = i % C;
        out[c * R + r] = in[i];
    }
}

// W2 [V_][H_] fp32 -> [NPAD][H_] bf16, zero-padded rows
__global__ void k_w2_to_bf16(const float* __restrict__ W2,
                             __hip_bfloat16* __restrict__ W2b) {
    int i = blockIdx.x * blockDim.x + threadIdx.x;
    if (i < NPAD * H_) {
        int n = i / H_;
        float v = (n < V_) ? W2[i] : 0.0f;
        W2b[i] = __float2bfloat16(v);
    }
}

// output 1: x flattened, as float (d_out is read back as one float32 buffer)
__global__ void k_write_x(const int* __restrict__ x, float* __restrict__ out) {
    int i = blockIdx.x * blockDim.x + threadIdx.x;
    if (i < NT) out[i] = (float)x[i];
}

// ---------------- LSTM phase ----------------
// One block per batch element. 1024 threads: thread g computes gate-row g of the
// [4H]=1024 gate vector (coalesced reads of transposed weights W[k][1024]).
// h/c state for all 3 layers lives in LDS. Sequential over T.
__global__ __launch_bounds__(1024) void k_lstm(
    const int* __restrict__ x, const float* __restrict__ h0,
    const float* __restrict__ c0, const float* __restrict__ emb,
    const float* __restrict__ WT,
    const float* __restrict__ bih1, const float* __restrict__ bhh1,
    const float* __restrict__ bih2, const float* __restrict__ bhh2,
    const float* __restrict__ bih3, const float* __restrict__ bhh3,
    float* __restrict__ h3_all) {
    const int n   = blockIdx.x;
    const int tid = threadIdx.x;

    const float* WihT1 = WT;                 // [16][1024]
    const float* WhhT1 = WT + 16   * G4;     // [256][1024]
    const float* WihT2 = WT + 272  * G4;
    const float* WhhT2 = WT + 528  * G4;
    const float* WihT3 = WT + 784  * G4;
    const float* WhhT3 = WT + 1040 * G4;

    __shared__ float h1[H_], c1[H_], h2[H_], c2[H_], h3[H_], c3[H_];
    __shared__ float e[E_];
    __shared__ float gbuf[G4];

    if (tid < H_) {
        float hv = h0[n * H_ + tid], cv = c0[n * H_ + tid];
        h1[tid] = hv; c1[tid] = cv;
        h2[tid] = hv; c2[tid] = cv;
        h3[tid] = hv; c3[tid] = cv;
    }
    const float b1s = bih1[tid] + bhh1[tid];
    const float b2s = bih2[tid] + bhh2[tid];
    const float b3s = bih3[tid] + bhh3[tid];
    __syncthreads();

    for (int t = 0; t < T_; ++t) {
        if (tid < E_) e[tid] = emb[(size_t)x[n * T_ + t] * E_ + tid];
        __syncthreads();

        // ---- layer 1: gates = e @ Wih1^T + h1 @ Whh1^T + b ----
        float acc = b1s;
        #pragma unroll
        for (int k = 0; k < E_; ++k)
            acc += e[k] * WihT1[k * G4 + tid];
        #pragma unroll 8
        for (int k = 0; k < H_; ++k)
            acc += h1[k] * WhhT1[k * G4 + tid];
        gbuf[tid] = acc;
        __syncthreads();
        if (tid < H_) {
            float gi = gbuf[tid], gf = gbuf[H_ + tid];
            float gg = gbuf[2 * H_ + tid], go = gbuf[3 * H_ + tid];
            float cn = sigmoidf_(gf) * c1[tid] + sigmoidf_(gi) * tanhf(gg);
            float hn = sigmoidf_(go) * tanhf(cn);
            c1[tid] = cn; h1[tid] = hn;
        }
        __syncthreads();

        // ---- layer 2 ----
        acc = b2s;
        #pragma unroll 8
        for (int k = 0; k < H_; ++k)
            acc += h1[k] * WihT2[k * G4 + tid];
        #pragma unroll 8
        for (int k = 0; k < H_; ++k)
            acc += h2[k] * WhhT2[k * G4 + tid];
        gbuf[tid] = acc;
        __syncthreads();
        if (tid < H_) {
            float gi = gbuf[tid], gf = gbuf[H_ + tid];
            float gg = gbuf[2 * H_ + tid], go = gbuf[3 * H_ + tid];
            float cn = sigmoidf_(gf) * c2[tid] + sigmoidf_(gi) * tanhf(gg);
            float hn = sigmoidf_(go) * tanhf(cn);
            c2[tid] = cn; h2[tid] = hn;
        }
        __syncthreads();

        // ---- layer 3 ----
        acc = b3s;
        #pragma unroll 8
        for (int k = 0; k < H_; ++k)
            acc += h2[k] * WihT3[k * G4 + tid];
        #pragma unroll 8
        for (int k = 0; k < H_; ++k)
            acc += h3[k] * WhhT3[k * G4 + tid];
        gbuf[tid] = acc;
        __syncthreads();
        if (tid < H_) {
            float gi = gbuf[tid], gf = gbuf[H_ + tid];
            float gg = gbuf[2 * H_ + tid], go = gbuf[3 * H_ + tid];
            float cn = sigmoidf_(gf) * c3[tid] + sigmoidf_(gi) * tanhf(gg);
            float hn = sigmoidf_(go) * tanhf(cn);
            c3[tid] = cn; h3[tid] = hn;
            h3_all[((size_t)n * T_ + t) * H_ + tid] = hn;
        }
        __syncthreads();
    }
}

// ---------------- head layer 1 ----------------
// Z[r][j] = bf16(relu(b1[j] + sum_k h3a[r][k] * W1[j][k])), W1T is [k][j]
__global__ __launch_bounds__(256) void k_head1(
    const float* __restrict__ h3a, const float* __restrict__ W1T,
    const float* __restrict__ b1, __hip_bfloat16* __restrict__ Z) {
    const int r = blockIdx.x, j = threadIdx.x;
    __shared__ float a[H_];
    a[j] = h3a[(size_t)r * H_ + j];
    __syncthreads();
    float s = b1[j];
    #pragma unroll 8
    for (int k = 0; k < H_; ++k)
        s += a[k] * W1T[k * H_ + j];
    Z[(size_t)r * H_ + j] = __float2bfloat16(fmaxf(s, 0.0f));
}

// ---------------- head layer 2: bf16 MFMA GEMM ----------------
// C[8192][20000] = Z[8192][256] @ W2b^T + b2.  W2b is [NPAD][256] (B^T layout).
// 128x128 C tile per block, 4 waves in 2x2, each wave 4x4 tiles of 16x16x32.
__global__ __launch_bounds__(256) void k_head2(
    const __hip_bfloat16* __restrict__ Zb, const __hip_bfloat16* __restrict__ W2b,
    const float* __restrict__ b2, float* __restrict__ out) {
    const int tid  = threadIdx.x;
    const int lane = tid & 63, wave = tid >> 6;
    const int wm = wave >> 1, wn = wave & 1;
    const int quad = lane >> 4, l16 = lane & 15;
    const int mbase = blockIdx.y * 128;
    const int nbase = blockIdx.x * 128;

    // stride 40 shorts (80 B): keeps 16B alignment, 2-way bank aliasing only (free)
    __shared__ short As[128 * 40];
    __shared__ short Bs[128 * 40];

    f32x4 acc[4][4] = {};

    const short* Ag = (const short*)Zb;
    const short* Bg = (const short*)W2b;

    for (int kk = 0; kk < H_; kk += 32) {
        __syncthreads();
        #pragma unroll
        for (int c = tid; c < 512; c += 256) {
            int r = c >> 2, p = (c & 3) * 8;
            *(int4*)&As[r * 40 + p] =
                *(const int4*)&Ag[(size_t)(mbase + r) * H_ + kk + p];
            *(int4*)&Bs[r * 40 + p] =
                *(const int4*)&Bg[(size_t)(nbase + r) * H_ + kk + p];
        }
        __syncthreads();

        short8 af[4], bfr[4];
        #pragma unroll
        for (int i = 0; i < 4; ++i)
            af[i] = *(const short8*)&As[(wm * 64 + i * 16 + l16) * 40 + quad * 8];
        #pragma unroll
        for (int j = 0; j < 4; ++j)
            bfr[j] = *(const short8*)&Bs[(wn * 64 + j * 16 + l16) * 40 + quad * 8];
        #pragma unroll
        for (int i = 0; i < 4; ++i)
            #pragma unroll
            for (int j = 0; j < 4; ++j)
                acc[i][j] = __builtin_amdgcn_mfma_f32_16x16x32_bf16(
                    af[i], bfr[j], acc[i][j], 0, 0, 0);
    }

    // epilogue: C/D layout col=lane&15, row=quad*4+reg  [verified m89/m91]
    #pragma unroll
    for (int j = 0; j < 4; ++j) {
        int gc = nbase + wn * 64 + j * 16 + l16;
        if (gc >= V_) continue;
        float bias = b2[gc];
        #pragma unroll
        for (int i = 0; i < 4; ++i) {
            int rbase = mbase + wm * 64 + i * 16 + quad * 4;
            #pragma unroll
            for (int reg = 0; reg < 4; ++reg)
                out[(size_t)(rbase + reg) * V_ + gc] = acc[i][j][reg] + bias;
        }
    }
}

// ---------------- launcher ----------------
extern "C" void kernel_launch(void* const* d_in, const int* in_sizes, int n_in,
                              void* d_out, int out_size, void* d_ws, size_t ws_size,
                              hipStream_t stream) {
    const int*   x    = (const int*)  d_in[0];
    const float* h0   = (const float*)d_in[1];
    const float* c0   = (const float*)d_in[2];
    const float* emb  = (const float*)d_in[3];
    const float* Wih1 = (const float*)d_in[4];
    const float* Whh1 = (const float*)d_in[5];
    const float* bih1 = (const float*)d_in[6];
    const float* bhh1 = (const float*)d_in[7];
    const float* Wih2 = (const float*)d_in[8];
    const float* Whh2 = (const float*)d_in[9];
    const float* bih2 = (const float*)d_in[10];
    const float* bhh2 = (const float*)d_in[11];
    const float* Wih3 = (const float*)d_in[12];
    const float* Whh3 = (const float*)d_in[13];
    const float* bih3 = (const float*)d_in[14];
    const float* bhh3 = (const float*)d_in[15];
    const float* W1   = (const float*)d_in[16];
    const float* b1   = (const float*)d_in[17];
    const float* W2   = (const float*)d_in[18];
    const float* b2   = (const float*)d_in[19];
    float* out = (float*)d_out;

    // workspace layout
    float* WT  = (float*)d_ws;                       // 1296*1024 fp32
    float* W1T = WT + 1296 * G4;                     // 256*256 fp32
    float* h3a = W1T + H_ * H_;                      // 8192*256 fp32
    __hip_bfloat16* Zb  = (__hip_bfloat16*)(h3a + (size_t)NT * H_);  // 8192*256 bf16
    __hip_bfloat16* W2b = Zb + (size_t)NT * H_;      // 20096*256 bf16

    // prep: transposed weights (coalesced [k][4H] reads in k_lstm)
    {
        int n;
        n = G4 * E_; k_transpose<<<(n + 255) / 256, 256, 0, stream>>>(Wih1, WT, G4, E_);
        n = G4 * H_;
        k_transpose<<<(n + 255) / 256, 256, 0, stream>>>(Whh1, WT + 16   * G4, G4, H_);
        k_transpose<<<(n + 255) / 256, 256, 0, stream>>>(Wih2, WT + 272  * G4, G4, H_);
        k_transpose<<<(n + 255) / 256, 256, 0, stream>>>(Whh2, WT + 528  * G4, G4, H_);
        k_transpose<<<(n + 255) / 256, 256, 0, stream>>>(Wih3, WT + 784  * G4, G4, H_);
        k_transpose<<<(n + 255) / 256, 256, 0, stream>>>(Whh3, WT + 1040 * G4, G4, H_);
        n = H_ * H_;
        k_transpose<<<(n + 255) / 256, 256, 0, stream>>>(W1, W1T, H_, H_);
    }
    k_w2_to_bf16<<<(NPAD * H_ + 255) / 256, 256, 0, stream>>>(W2, W2b);
    k_write_x<<<(NT + 255) / 256, 256, 0, stream>>>(x, out + (size_t)NT * V_);

    // recurrent phase: one block per batch chain
    k_lstm<<<N_, 1024, 0, stream>>>(x, h0, c0, emb, WT,
                                    bih1, bhh1, bih2, bhh2, bih3, bhh3, h3a);

    // head
    k_head1<<<NT, 256, 0, stream>>>(h3a, W1T, b1, Zb);
    dim3 g2(NPAD / 128, NT / 128);
    k_head2<<<g2, 256, 0, stream>>>(Zb, W2b, b2, out);
}